// Round 15
// baseline (68.097 us; speedup 1.0000x reference)
//
#include <hip/hip_runtime.h>
#include <hip/hip_bf16.h>

typedef __attribute__((ext_vector_type(8))) short bf16x8;
typedef __attribute__((ext_vector_type(4))) float f32x4;

#define EPS 1e-5f
#define K2L 2.8853900817779268f   // 2*log2(e): folds exp(2y) -> exp2(y*K2L)

// ws layout: frag blocks (182 x 1KB bf16), fp32 ST region, then flag
#define N_FRAG_BLOCKS 182
#define WSB_LEAF 0      // 64 blocks: leaf l
#define WSB_MID  64     // 80 blocks: m*10 + tt*5 + s   (K = [hl(128), xm(16), 0(16)])
#define WSB_ROOT 144    // 36 blocks: tt*9 + s
#define WSB_HEAD 180    // 2 blocks: s
#define ST_SL 0
#define ST_TL 1024
#define ST_SM 2048
#define ST_TM 2304
#define ST_SR 2560
#define ST_TR 2624
#define WS_ST_BYTE_OFF (N_FRAG_BLOCKS * 1024)
#define FLAG_BYTE_OFF  197632          // past frags (186368) + ST (10752)
#define NPREP 24                        // blocks carrying prep slices

#define XSW 1192   // u16 stride of staged x rows (2384 B; 2-way bank alias max)

__device__ __forceinline__ unsigned short f2bf(float f) {  // RNE float->bf16
    unsigned u = __float_as_uint(f);
    unsigned r = u + 0x7fffu + ((u >> 16) & 1u);
    return (unsigned short)(r >> 16);
}

// packed f32x2 -> bf16x2 (RNE)
__device__ __forceinline__ unsigned pk2(float a, float b) {
    float2 f2; f2.x = a; f2.y = b;
    __hip_bfloat162 h = __float22bfloat162_rn(f2);
    union { __hip_bfloat162 h2; unsigned u; } cv; cv.h2 = h;
    return cv.u;
}

// BN+tanh with pre-folded scale: arg = acc*S' + T' (S',T' carry 2*log2e)
__device__ __forceinline__ float bn_act(float acc, float Sp, float Tp) {
    float e = exp2f(fmaf(acc, Sp, Tp));
    float r = __builtin_amdgcn_rcpf(e + 1.0f);
    return fmaf(-2.0f, r, 1.0f);
}

// ---------------- fused kernel: prep slices + flag + compute ---------------
// Grid = 1024 blocks x 512 thr; 38144 B LDS + <=64 VGPR -> 4 blocks/CU ->
// ALL blocks co-resident (spin-wait is deadlock-free). Blocks 0..23 compute
// the weight-frag/ST tables (prep) then release via fence+atomicAdd; every
// block stages its x tile FIRST (overlaps prep), spin-acquires the flag,
// then runs the verified R14 compute phases (in-place LDS, 3 barriers).
__global__ __launch_bounds__(512, 8) void ontology_fused(
    const float* __restrict__ x,
    const float* __restrict__ Wl, const float* __restrict__ Wm,
    const float* __restrict__ Wr, const float* __restrict__ Wh,
    const float* __restrict__ bl, const float* __restrict__ gl,
    const float* __restrict__ betal, const float* __restrict__ ml,
    const float* __restrict__ vl,
    const float* __restrict__ bm, const float* __restrict__ gm,
    const float* __restrict__ betam, const float* __restrict__ mm,
    const float* __restrict__ vm,
    const float* __restrict__ br, const float* __restrict__ gr,
    const float* __restrict__ betar, const float* __restrict__ mr,
    const float* __restrict__ vr,
    const float* __restrict__ bh,
    unsigned short* __restrict__ wsFrag, float* __restrict__ wsST,
    int* __restrict__ flagp,
    float* __restrict__ out)
{
    __shared__ __align__(16) unsigned short xs[16 * XSW];   // 38144 B

    const int tid  = threadIdx.x;
    const int bid  = blockIdx.x;
    const int w    = tid >> 6;
    const int lane = tid & 63;
    const int c    = lane & 15;       // sample within tile
    const int g    = lane >> 4;       // k/feat group
    const int rowbase = bid * 16;

    // ================= prep slice (blocks 0..23) =================
    if (bid < NPREP) {
        if (bid < 23) {
            const int b = bid * 8 + (tid >> 6);      // 8 frag blocks / GPU block
            if (b < N_FRAG_BLOCKS) {
                const int t = tid & 63;
                const int row = t & 15, gg = t >> 4;
                unsigned short vals[8];
                #pragma unroll
                for (int i = 0; i < 8; ++i) {
                    const int k = gg * 8 + i;
                    float v = 0.f;
                    if (b < 64) {                       // leaf l: pair-packed K
                        const int l = b;
                        if ((l & 1) == 0) { if (k < 16)  v = Wl[l * 256 + k * 16 + row]; }
                        else              { if (k >= 16) v = Wl[l * 256 + (k - 16) * 16 + row]; }
                    } else if (b < 144) {               // mid: K=[hl,xm,0]
                        const int idx = b - 64, m = idx / 10, rem = idx % 10;
                        const int tt = rem / 5, s = rem % 5;
                        const int j = s * 32 + k;
                        const int krow = (j < 128) ? (16 + j) : ((j < 144) ? (j - 128) : -1);
                        if (krow >= 0) v = Wm[m * 4608 + krow * 32 + tt * 16 + row];
                    } else if (b < 180) {               // root: tt*9 + s
                        const int idx = b - 144, tt = idx / 9, s = idx % 9;
                        if (s == 0) { if (k < 16) v = Wr[k * 64 + tt * 16 + row]; }
                        else { const int krow = 16 + (s - 1) * 32 + k;
                               v = Wr[krow * 64 + tt * 16 + row]; }
                    } else {                            // head
                        const int s = b - 180, krow = s * 32 + k;
                        if (row < 10) v = Wh[krow * 10 + row];
                    }
                    vals[i] = f2bf(v);
                }
                #pragma unroll
                for (int i = 0; i < 8; ++i) wsFrag[b * 512 + t * 8 + i] = vals[i];
            }
        } else if (tid < 256) {                          // bid==23: ST tables
            #pragma unroll
            for (int i = 0; i < 4; ++i) {
                const int id = tid + 256 * i;
                const float S = gl[id] * rsqrtf(vl[id] + EPS);
                wsST[ST_SL + id] = S * K2L;
                wsST[ST_TL + id] = ((bl[id] - ml[id]) * S + betal[id]) * K2L;
            }
            {
                const int id = tid;
                const float S = gm[id] * rsqrtf(vm[id] + EPS);
                wsST[ST_SM + id] = S * K2L;
                wsST[ST_TM + id] = ((bm[id] - mm[id]) * S + betam[id]) * K2L;
            }
            if (tid < 64) {
                const int id = tid;
                const float S = gr[id] * rsqrtf(vr[id] + EPS);
                wsST[ST_SR + id] = S * K2L;
                wsST[ST_TR + id] = ((br[id] - mr[id]) * S + betar[id]) * K2L;
            }
        }
        __syncthreads();                                 // slice stores done
        if (tid == 0) {
            __threadfence();                             // device-scope release
            atomicAdd(flagp, 1);
        }
    }

    // ================= phase 0: batched contiguous x staging =================
    {
        const int srow = tid >> 5;
        const int j    = tid & 31;
        const float4* xr4 = (const float4*)(x + (size_t)(rowbase + srow) * 1168);
        unsigned short* xsrow = xs + srow * XSW;

        float4 v0, v1, v2, v3, v4;
        v0 = xr4[j];       v1 = xr4[j + 32];  v2 = xr4[j + 64];
        v3 = xr4[j + 96];  v4 = xr4[j + 128];
        {
            uint2 p;
            p.x = pk2(v0.x, v0.y); p.y = pk2(v0.z, v0.w); *(uint2*)(xsrow + (j      ) * 4) = p;
            p.x = pk2(v1.x, v1.y); p.y = pk2(v1.z, v1.w); *(uint2*)(xsrow + (j +  32) * 4) = p;
            p.x = pk2(v2.x, v2.y); p.y = pk2(v2.z, v2.w); *(uint2*)(xsrow + (j +  64) * 4) = p;
            p.x = pk2(v3.x, v3.y); p.y = pk2(v3.z, v3.w); *(uint2*)(xsrow + (j +  96) * 4) = p;
            p.x = pk2(v4.x, v4.y); p.y = pk2(v4.z, v4.w); *(uint2*)(xsrow + (j + 128) * 4) = p;
        }
        v0 = xr4[j + 160]; v1 = xr4[j + 192]; v2 = xr4[j + 224]; v3 = xr4[j + 256];
        const bool has9 = (j < 4);
        if (has9) v4 = xr4[j + 288];
        {
            uint2 p;
            p.x = pk2(v0.x, v0.y); p.y = pk2(v0.z, v0.w); *(uint2*)(xsrow + (j + 160) * 4) = p;
            p.x = pk2(v1.x, v1.y); p.y = pk2(v1.z, v1.w); *(uint2*)(xsrow + (j + 192) * 4) = p;
            p.x = pk2(v2.x, v2.y); p.y = pk2(v2.z, v2.w); *(uint2*)(xsrow + (j + 224) * 4) = p;
            p.x = pk2(v3.x, v3.y); p.y = pk2(v3.z, v3.w); *(uint2*)(xsrow + (j + 256) * 4) = p;
            if (has9) {
                p.x = pk2(v4.x, v4.y); p.y = pk2(v4.z, v4.w);
                *(uint2*)(xsrow + (j + 288) * 4) = p;
            }
        }
        if (tid < 64) {                               // zero cols 1168..1183
            const int zr = tid >> 2, seg = tid & 3;
            uint2 z; z.x = 0u; z.y = 0u;
            *(uint2*)(xs + zr * XSW + 1168 + seg * 4) = z;
        }
    }

    // ---- spin-acquire prep flag (hidden under staging latency) ----
    if (tid == 0) {
        while (__hip_atomic_load(flagp, __ATOMIC_ACQUIRE, __HIP_MEMORY_SCOPE_AGENT) < NPREP)
            __builtin_amdgcn_s_sleep(2);
    }
    __syncthreads();   // B1: slab staged + ws visible

    const float* Sl = wsST + ST_SL; const float* Tl = wsST + ST_TL;
    const float* Sm = wsST + ST_SM; const float* Tm = wsST + ST_TM;
    const float* Sr = wsST + ST_SR; const float* Tr = wsST + ST_TR;

    // ---- wave w: 8 leaves of mid w (B-frags from slab, outputs in place) ---
    const int colbase = w * 128;
    #pragma unroll
    for (int p = 0; p < 4; ++p) {
        bf16x8 bfrag = *(const bf16x8*)(xs + c * XSW + colbase + p * 32 + g * 8);
        #pragma unroll
        for (int e = 0; e < 2; ++e) {
            const int l = 2 * p + e, leaf = w * 8 + l;
            bf16x8 afrag = *(const bf16x8*)(wsFrag + (WSB_LEAF + leaf) * 512 + lane * 8);
            f32x4 zz = {0.f,0.f,0.f,0.f};
            f32x4 acc = __builtin_amdgcn_mfma_f32_16x16x32_bf16(afrag, bfrag, zz, 0, 0, 0);
            const int po = leaf * 16 + 4 * g;
            float4 S = *(const float4*)(Sl + po);
            float4 T = *(const float4*)(Tl + po);
            uint2 pk;
            pk.x = pk2(bn_act(acc[0], S.x, T.x), bn_act(acc[1], S.y, T.y));
            pk.y = pk2(bn_act(acc[2], S.z, T.z), bn_act(acc[3], S.w, T.w));
            *(uint2*)(xs + c * XSW + colbase + l * 16 + 4 * g) = pk;
        }
    }

    // ---- mid w: K = [hl(128) at colbase, xm(16)+pad at 1024+w*16] ---------
    {
        f32x4 acc0 = {0.f,0.f,0.f,0.f};
        f32x4 acc1 = {0.f,0.f,0.f,0.f};
        const unsigned short* fb = wsFrag + (WSB_MID + w * 10) * 512 + lane * 8;
        #pragma unroll
        for (int s = 0; s < 5; ++s) {
            const int cc = (s < 4) ? (colbase + s * 32) : (1024 + w * 16);
            bf16x8 bfrag = *(const bf16x8*)(xs + c * XSW + cc + g * 8);
            bf16x8 a0 = *(const bf16x8*)(fb + s * 512);
            bf16x8 a1 = *(const bf16x8*)(fb + (5 + s) * 512);
            acc0 = __builtin_amdgcn_mfma_f32_16x16x32_bf16(a0, bfrag, acc0, 0, 0, 0);
            acc1 = __builtin_amdgcn_mfma_f32_16x16x32_bf16(a1, bfrag, acc1, 0, 0, 0);
        }
        #pragma unroll
        for (int tt = 0; tt < 2; ++tt) {
            f32x4 acc = tt ? acc1 : acc0;
            const int po = w * 32 + tt * 16 + 4 * g;
            float4 S = *(const float4*)(Sm + po);
            float4 T = *(const float4*)(Tm + po);
            uint2 pk;
            pk.x = pk2(bn_act(acc[0], S.x, T.x), bn_act(acc[1], S.y, T.y));
            pk.y = pk2(bn_act(acc[2], S.z, T.z), bn_act(acc[3], S.w, T.w));
            *(uint2*)(xs + c * XSW + colbase + tt * 16 + 4 * g) = pk;
        }
    }
    __syncthreads();   // B2: all hm slabs in place

    // ---- root col-tile w (waves 0..3): s=0 from x cols 1152, s=1..8 hm -----
    if (w < 4) {
        const unsigned short* fb = wsFrag + (WSB_ROOT + w * 9) * 512 + lane * 8;
        f32x4 acc = {0.f,0.f,0.f,0.f};
        {
            bf16x8 bfrag = *(const bf16x8*)(xs + c * XSW + 1152 + g * 8);
            bf16x8 a0 = *(const bf16x8*)fb;
            acc = __builtin_amdgcn_mfma_f32_16x16x32_bf16(a0, bfrag, acc, 0, 0, 0);
        }
        #pragma unroll
        for (int s = 1; s <= 8; ++s) {
            bf16x8 bfrag = *(const bf16x8*)(xs + c * XSW + (s - 1) * 128 + g * 8);
            bf16x8 a0 = *(const bf16x8*)(fb + s * 512);
            acc = __builtin_amdgcn_mfma_f32_16x16x32_bf16(a0, bfrag, acc, 0, 0, 0);
        }
        const int po = w * 16 + 4 * g;
        float4 S = *(const float4*)(Sr + po);
        float4 T = *(const float4*)(Tr + po);
        uint2 pk;
        pk.x = pk2(bn_act(acc[0], S.x, T.x), bn_act(acc[1], S.y, T.y));
        pk.y = pk2(bn_act(acc[2], S.z, T.z), bn_act(acc[3], S.w, T.w));
        *(uint2*)(xs + c * XSW + 32 + w * 16 + 4 * g) = pk;
    }
    __syncthreads();   // B3: hr complete

    // ---- head (wave 0): tasks in rows, samples in cols ----
    if (w == 0) {
        f32x4 acc = {0.f,0.f,0.f,0.f};
        #pragma unroll
        for (int s = 0; s < 2; ++s) {
            bf16x8 bfrag = *(const bf16x8*)(xs + c * XSW + 32 + s * 32 + g * 8);
            bf16x8 a0 = *(const bf16x8*)(wsFrag + (WSB_HEAD + s) * 512 + lane * 8);
            acc = __builtin_amdgcn_mfma_f32_16x16x32_bf16(a0, bfrag, acc, 0, 0, 0);
        }
        float* op = out + (size_t)(rowbase + c) * 10 + 4 * g;
        if (g < 2) {
            float2 o1 = {acc[0] + bh[4 * g],     acc[1] + bh[4 * g + 1]};
            float2 o2 = {acc[2] + bh[4 * g + 2], acc[3] + bh[4 * g + 3]};
            *(float2*)op = o1;
            *(float2*)(op + 2) = o2;
        } else if (g == 2) {
            float2 o1 = {acc[0] + bh[8], acc[1] + bh[9]};
            *(float2*)op = o1;
        }
    }
}

extern "C" void kernel_launch(void* const* d_in, const int* in_sizes, int n_in,
                              void* d_out, int out_size, void* d_ws, size_t ws_size,
                              hipStream_t stream) {
    const float* x     = (const float*)d_in[0];
    const float* Wl    = (const float*)d_in[1];
    const float* bl    = (const float*)d_in[2];
    const float* gl    = (const float*)d_in[3];
    const float* betal = (const float*)d_in[4];
    const float* ml    = (const float*)d_in[5];
    const float* vl    = (const float*)d_in[6];
    const float* Wm    = (const float*)d_in[7];
    const float* bm    = (const float*)d_in[8];
    const float* gm    = (const float*)d_in[9];
    const float* betam = (const float*)d_in[10];
    const float* mm    = (const float*)d_in[11];
    const float* vm    = (const float*)d_in[12];
    const float* Wr    = (const float*)d_in[13];
    const float* br    = (const float*)d_in[14];
    const float* gr    = (const float*)d_in[15];
    const float* betar = (const float*)d_in[16];
    const float* mr    = (const float*)d_in[17];
    const float* vr    = (const float*)d_in[18];
    const float* Wh    = (const float*)d_in[19];
    const float* bh    = (const float*)d_in[20];
    float* out = (float*)d_out;

    unsigned short* wsFrag = (unsigned short*)d_ws;
    float* wsST = (float*)((char*)d_ws + WS_ST_BYTE_OFF);
    int* flagp = (int*)((char*)d_ws + FLAG_BYTE_OFF);

    hipMemsetAsync(flagp, 0, 4, stream);   // zero the release flag each call

    const int n = in_sizes[0] / 1168;   // 16384
    ontology_fused<<<n / 16, 512, 0, stream>>>(
        x, Wl, Wm, Wr, Wh, bl, gl, betal, ml, vl, bm, gm, betam, mm, vm,
        br, gr, betar, mr, vr, bh, wsFrag, wsST, flagp, out);
}

// Round 16
// 30.588 us; speedup vs baseline: 2.2263x; 2.2263x over previous
//
#include <hip/hip_runtime.h>
#include <hip/hip_bf16.h>

typedef __attribute__((ext_vector_type(8))) short bf16x8;
typedef __attribute__((ext_vector_type(4))) float f32x4;

#define EPS 1e-5f
#define K2L 2.8853900817779268f   // 2*log2(e): tanh(z)=1-2/(exp2(z*K2L)+1)

// ws layout: frag blocks (182 x 1KB bf16, BN-scale PRE-FOLDED) then fp32 T region
#define N_FRAG_BLOCKS 182
#define WSB_LEAF 0      // 64 blocks: leaf l
#define WSB_MID  64     // 80 blocks: m*10 + tt*5 + s   (K = [hl(128), xm(16), 0(16)])
#define WSB_ROOT 144    // 36 blocks: tt*9 + s
#define WSB_HEAD 180    // 2 blocks: s (unscaled)
#define ST_TL 0         // leaf T'' (1024)
#define ST_TM 1024      // mid  T'' (256)
#define ST_TR 1280      // root T'' (64)
#define ST_TH 1344      // head bias padded (16)
#define WS_ST_BYTE_OFF (N_FRAG_BLOCKS * 1024)

#define XSW 1192   // u16 stride of staged x rows (2384 B; 2-way bank alias max)

__device__ __forceinline__ unsigned short f2bf(float f) {  // RNE float->bf16
    unsigned u = __float_as_uint(f);
    unsigned r = u + 0x7fffu + ((u >> 16) & 1u);
    return (unsigned short)(r >> 16);
}

// packed f32x2 -> bf16x2 (RNE)
__device__ __forceinline__ unsigned pk2(float a, float b) {
    float2 f2; f2.x = a; f2.y = b;
    __hip_bfloat162 h = __float22bfloat162_rn(f2);
    union { __hip_bfloat162 h2; unsigned u; } cv; cv.h2 = h;
    return cv.u;
}

// tanh of pre-scaled arg (scale folded into weights + T): 1 - 2/(exp2(z)+1)
__device__ __forceinline__ float bn_act2(float z) {
    float e = exp2f(z);
    float r = __builtin_amdgcn_rcpf(e + 1.0f);
    return fmaf(-2.0f, r, 1.0f);
}

// ---------------- prep: scale-folded bf16 frags + T'' tables ---------------
__global__ void ontology_prep(
    const float* __restrict__ Wl, const float* __restrict__ Wm,
    const float* __restrict__ Wr, const float* __restrict__ Wh,
    const float* __restrict__ bl, const float* __restrict__ gl,
    const float* __restrict__ betal, const float* __restrict__ ml,
    const float* __restrict__ vl,
    const float* __restrict__ bm, const float* __restrict__ gm,
    const float* __restrict__ betam, const float* __restrict__ mm,
    const float* __restrict__ vm,
    const float* __restrict__ br, const float* __restrict__ gr,
    const float* __restrict__ betar, const float* __restrict__ mr,
    const float* __restrict__ vr,
    const float* __restrict__ bh,
    unsigned short* __restrict__ wsFrag, float* __restrict__ wsST)
{
    const int tid = threadIdx.x;
    if (blockIdx.x < 46) {
        const int b = blockIdx.x * 4 + (tid >> 6);
        if (b >= N_FRAG_BLOCKS) return;
        const int t = tid & 63;
        const int row = t & 15, g = t >> 4;
        // per-row BN scale (folded into the weights), K2L included except head
        float scale;
        if (b < 64) {
            const int id = b * 16 + row;
            scale = gl[id] * rsqrtf(vl[id] + EPS) * K2L;
        } else if (b < 144) {
            const int idx = b - 64, m = idx / 10, rem = idx % 10, tt = rem / 5;
            const int id = m * 32 + tt * 16 + row;
            scale = gm[id] * rsqrtf(vm[id] + EPS) * K2L;
        } else if (b < 180) {
            const int idx = b - 144, tt = idx / 9;
            const int id = tt * 16 + row;
            scale = gr[id] * rsqrtf(vr[id] + EPS) * K2L;
        } else {
            scale = 1.0f;                      // head: no BN, no tanh
        }
        unsigned short vals[8];
        #pragma unroll
        for (int i = 0; i < 8; ++i) {
            const int k = g * 8 + i;
            float v = 0.f;
            if (b < 64) {                       // leaf l: pair-packed K
                const int l = b;
                if ((l & 1) == 0) { if (k < 16)  v = Wl[l * 256 + k * 16 + row]; }
                else              { if (k >= 16) v = Wl[l * 256 + (k - 16) * 16 + row]; }
            } else if (b < 144) {               // mid: K=[hl,xm,0]
                const int idx = b - 64, m = idx / 10, rem = idx % 10;
                const int tt = rem / 5, s = rem % 5;
                const int j = s * 32 + k;
                const int krow = (j < 128) ? (16 + j) : ((j < 144) ? (j - 128) : -1);
                if (krow >= 0) v = Wm[m * 4608 + krow * 32 + tt * 16 + row];
            } else if (b < 180) {               // root: tt*9 + s
                const int idx = b - 144, tt = idx / 9, s = idx % 9;
                if (s == 0) { if (k < 16) v = Wr[k * 64 + tt * 16 + row]; }
                else { const int krow = 16 + (s - 1) * 32 + k;
                       v = Wr[krow * 64 + tt * 16 + row]; }
            } else {                            // head
                const int s = b - 180, krow = s * 32 + k;
                if (row < 10) v = Wh[krow * 10 + row];
            }
            vals[i] = f2bf(v * scale);
        }
        #pragma unroll
        for (int i = 0; i < 8; ++i) wsFrag[b * 512 + t * 8 + i] = vals[i];
    } else {
        // T'' tables (K2L-folded); head bias padded to 16
        #pragma unroll
        for (int i = 0; i < 4; ++i) {
            const int id = tid + 256 * i;
            const float S = gl[id] * rsqrtf(vl[id] + EPS);
            wsST[ST_TL + id] = ((bl[id] - ml[id]) * S + betal[id]) * K2L;
        }
        {
            const int id = tid;
            const float S = gm[id] * rsqrtf(vm[id] + EPS);
            wsST[ST_TM + id] = ((bm[id] - mm[id]) * S + betam[id]) * K2L;
        }
        if (tid < 64) {
            const int id = tid;
            const float S = gr[id] * rsqrtf(vr[id] + EPS);
            wsST[ST_TR + id] = ((br[id] - mr[id]) * S + betar[id]) * K2L;
        }
        if (tid < 16) {
            wsST[ST_TH + tid] = (tid < 10) ? bh[tid] : 0.f;
        }
    }
}

// ---------------- main: R14 structure + T-as-accinit (no S/T post-loads) ---
__global__ __launch_bounds__(512, 8) void ontology_mfma(
    const float* __restrict__ x,
    const unsigned short* __restrict__ wsFrag,
    const float* __restrict__ wsST,
    float* __restrict__ out)
{
    __shared__ __align__(16) unsigned short xs[16 * XSW];   // 38144 B

    const int tid  = threadIdx.x;
    const int w    = tid >> 6;
    const int lane = tid & 63;
    const int c    = lane & 15;       // sample within tile
    const int g    = lane >> 4;       // k/feat group
    const int rowbase = blockIdx.x * 16;

    const float* Tl = wsST + ST_TL;
    const float* Tm = wsST + ST_TM;
    const float* Tr = wsST + ST_TR;
    const float* Th = wsST + ST_TH;

    // ---- phase 0: batched contiguous stage of x tile -> bf16 slab ----
    {
        const int srow = tid >> 5;
        const int j    = tid & 31;
        const float4* xr4 = (const float4*)(x + (size_t)(rowbase + srow) * 1168);
        unsigned short* xsrow = xs + srow * XSW;

        float4 v0, v1, v2, v3, v4;
        v0 = xr4[j];       v1 = xr4[j + 32];  v2 = xr4[j + 64];
        v3 = xr4[j + 96];  v4 = xr4[j + 128];
        {
            uint2 p;
            p.x = pk2(v0.x, v0.y); p.y = pk2(v0.z, v0.w); *(uint2*)(xsrow + (j      ) * 4) = p;
            p.x = pk2(v1.x, v1.y); p.y = pk2(v1.z, v1.w); *(uint2*)(xsrow + (j +  32) * 4) = p;
            p.x = pk2(v2.x, v2.y); p.y = pk2(v2.z, v2.w); *(uint2*)(xsrow + (j +  64) * 4) = p;
            p.x = pk2(v3.x, v3.y); p.y = pk2(v3.z, v3.w); *(uint2*)(xsrow + (j +  96) * 4) = p;
            p.x = pk2(v4.x, v4.y); p.y = pk2(v4.z, v4.w); *(uint2*)(xsrow + (j + 128) * 4) = p;
        }
        v0 = xr4[j + 160]; v1 = xr4[j + 192]; v2 = xr4[j + 224]; v3 = xr4[j + 256];
        const bool has9 = (j < 4);
        if (has9) v4 = xr4[j + 288];
        {
            uint2 p;
            p.x = pk2(v0.x, v0.y); p.y = pk2(v0.z, v0.w); *(uint2*)(xsrow + (j + 160) * 4) = p;
            p.x = pk2(v1.x, v1.y); p.y = pk2(v1.z, v1.w); *(uint2*)(xsrow + (j + 192) * 4) = p;
            p.x = pk2(v2.x, v2.y); p.y = pk2(v2.z, v2.w); *(uint2*)(xsrow + (j + 224) * 4) = p;
            p.x = pk2(v3.x, v3.y); p.y = pk2(v3.z, v3.w); *(uint2*)(xsrow + (j + 256) * 4) = p;
            if (has9) {
                p.x = pk2(v4.x, v4.y); p.y = pk2(v4.z, v4.w);
                *(uint2*)(xsrow + (j + 288) * 4) = p;
            }
        }
        if (tid < 64) {                               // zero cols 1168..1183
            const int zr = tid >> 2, seg = tid & 3;
            uint2 z; z.x = 0u; z.y = 0u;
            *(uint2*)(xs + zr * XSW + 1168 + seg * 4) = z;
        }
    }
    __syncthreads();   // B1: slab staged

    // ---- wave w: 8 leaves of mid w (T'' as acc-init; outputs in place) -----
    const int colbase = w * 128;
    #pragma unroll
    for (int p = 0; p < 4; ++p) {
        bf16x8 bfrag = *(const bf16x8*)(xs + c * XSW + colbase + p * 32 + g * 8);
        #pragma unroll
        for (int e = 0; e < 2; ++e) {
            const int l = 2 * p + e, leaf = w * 8 + l;
            bf16x8 afrag = *(const bf16x8*)(wsFrag + (WSB_LEAF + leaf) * 512 + lane * 8);
            const int po = leaf * 16 + 4 * g;
            float4 T = *(const float4*)(Tl + po);
            f32x4 ci = {T.x, T.y, T.z, T.w};
            f32x4 acc = __builtin_amdgcn_mfma_f32_16x16x32_bf16(afrag, bfrag, ci, 0, 0, 0);
            uint2 pk;
            pk.x = pk2(bn_act2(acc[0]), bn_act2(acc[1]));
            pk.y = pk2(bn_act2(acc[2]), bn_act2(acc[3]));
            *(uint2*)(xs + c * XSW + colbase + l * 16 + 4 * g) = pk;
        }
    }

    // ---- mid w: K = [hl(128) at colbase, xm(16)+pad at 1024+w*16] ---------
    {
        float4 T0 = *(const float4*)(Tm + w * 32 + 4 * g);
        float4 T1 = *(const float4*)(Tm + w * 32 + 16 + 4 * g);
        f32x4 acc0 = {T0.x, T0.y, T0.z, T0.w};
        f32x4 acc1 = {T1.x, T1.y, T1.z, T1.w};
        const unsigned short* fb = wsFrag + (WSB_MID + w * 10) * 512 + lane * 8;
        #pragma unroll
        for (int s = 0; s < 5; ++s) {
            const int cc = (s < 4) ? (colbase + s * 32) : (1024 + w * 16);
            bf16x8 bfrag = *(const bf16x8*)(xs + c * XSW + cc + g * 8);
            bf16x8 a0 = *(const bf16x8*)(fb + s * 512);
            bf16x8 a1 = *(const bf16x8*)(fb + (5 + s) * 512);
            acc0 = __builtin_amdgcn_mfma_f32_16x16x32_bf16(a0, bfrag, acc0, 0, 0, 0);
            acc1 = __builtin_amdgcn_mfma_f32_16x16x32_bf16(a1, bfrag, acc1, 0, 0, 0);
        }
        #pragma unroll
        for (int tt = 0; tt < 2; ++tt) {
            f32x4 acc = tt ? acc1 : acc0;
            uint2 pk;
            pk.x = pk2(bn_act2(acc[0]), bn_act2(acc[1]));
            pk.y = pk2(bn_act2(acc[2]), bn_act2(acc[3]));
            *(uint2*)(xs + c * XSW + colbase + tt * 16 + 4 * g) = pk;
        }
    }
    __syncthreads();   // B2: all hm slabs in place

    // ---- root col-tile w (waves 0..3): s=0 from x cols 1152, s=1..8 hm -----
    if (w < 4) {
        const unsigned short* fb = wsFrag + (WSB_ROOT + w * 9) * 512 + lane * 8;
        float4 T = *(const float4*)(Tr + w * 16 + 4 * g);
        f32x4 acc = {T.x, T.y, T.z, T.w};
        {
            bf16x8 bfrag = *(const bf16x8*)(xs + c * XSW + 1152 + g * 8);
            bf16x8 a0 = *(const bf16x8*)fb;
            acc = __builtin_amdgcn_mfma_f32_16x16x32_bf16(a0, bfrag, acc, 0, 0, 0);
        }
        #pragma unroll
        for (int s = 1; s <= 8; ++s) {
            bf16x8 bfrag = *(const bf16x8*)(xs + c * XSW + (s - 1) * 128 + g * 8);
            bf16x8 a0 = *(const bf16x8*)(fb + s * 512);
            acc = __builtin_amdgcn_mfma_f32_16x16x32_bf16(a0, bfrag, acc, 0, 0, 0);
        }
        uint2 pk;
        pk.x = pk2(bn_act2(acc[0]), bn_act2(acc[1]));
        pk.y = pk2(bn_act2(acc[2]), bn_act2(acc[3]));
        *(uint2*)(xs + c * XSW + 32 + w * 16 + 4 * g) = pk;
    }
    __syncthreads();   // B3: hr complete

    // ---- head (wave 0): bias as acc-init, direct store --------------------
    if (w == 0) {
        float4 T = *(const float4*)(Th + 4 * g);
        f32x4 acc = {T.x, T.y, T.z, T.w};
        #pragma unroll
        for (int s = 0; s < 2; ++s) {
            bf16x8 bfrag = *(const bf16x8*)(xs + c * XSW + 32 + s * 32 + g * 8);
            bf16x8 a0 = *(const bf16x8*)(wsFrag + (WSB_HEAD + s) * 512 + lane * 8);
            acc = __builtin_amdgcn_mfma_f32_16x16x32_bf16(a0, bfrag, acc, 0, 0, 0);
        }
        float* op = out + (size_t)(rowbase + c) * 10 + 4 * g;
        if (g < 2) {
            float2 o1 = {acc[0], acc[1]};
            float2 o2 = {acc[2], acc[3]};
            *(float2*)op = o1;
            *(float2*)(op + 2) = o2;
        } else if (g == 2) {
            float2 o1 = {acc[0], acc[1]};
            *(float2*)op = o1;
        }
    }
}

extern "C" void kernel_launch(void* const* d_in, const int* in_sizes, int n_in,
                              void* d_out, int out_size, void* d_ws, size_t ws_size,
                              hipStream_t stream) {
    const float* x     = (const float*)d_in[0];
    const float* Wl    = (const float*)d_in[1];
    const float* bl    = (const float*)d_in[2];
    const float* gl    = (const float*)d_in[3];
    const float* betal = (const float*)d_in[4];
    const float* ml    = (const float*)d_in[5];
    const float* vl    = (const float*)d_in[6];
    const float* Wm    = (const float*)d_in[7];
    const float* bm    = (const float*)d_in[8];
    const float* gm    = (const float*)d_in[9];
    const float* betam = (const float*)d_in[10];
    const float* mm    = (const float*)d_in[11];
    const float* vm    = (const float*)d_in[12];
    const float* Wr    = (const float*)d_in[13];
    const float* br    = (const float*)d_in[14];
    const float* gr    = (const float*)d_in[15];
    const float* betar = (const float*)d_in[16];
    const float* mr    = (const float*)d_in[17];
    const float* vr    = (const float*)d_in[18];
    const float* Wh    = (const float*)d_in[19];
    const float* bh    = (const float*)d_in[20];
    float* out = (float*)d_out;

    unsigned short* wsFrag = (unsigned short*)d_ws;
    float* wsST = (float*)((char*)d_ws + WS_ST_BYTE_OFF);

    ontology_prep<<<47, 256, 0, stream>>>(
        Wl, Wm, Wr, Wh, bl, gl, betal, ml, vl, bm, gm, betam, mm, vm,
        br, gr, betar, mr, vr, bh, wsFrag, wsST);

    const int n = in_sizes[0] / 1168;   // 16384
    ontology_mfma<<<n / 16, 512, 0, stream>>>(x, wsFrag, wsST, out);
}